// Round 6
// baseline (390.583 us; speedup 1.0000x reference)
//
#include <hip/hip_runtime.h>

// ---------------------------------------------------------------------------
// DeformableTransformerEncoderLayer on MI355X (gfx950) — round 6
// Stall-surgery on the R5 fusion (R5: ffn_k 130us at 8% MFMA / 6% VALU /
// 5% HBM = latency-bound):
//  * no LDS "patch" transpose anywhere: stores go straight from MFMA
//    C-layout (col=lane&15, row=quad*4+r) as dword/b16 scatter
//  * register double-buffering of all B/W fragments across the K-loop
//  * BM=32 blocks, 17-34 KB LDS -> 3-8 blocks/CU for latency hiding
//  * LN fused in epilogue: 16-lane shfl row-sums + LDS atomicAdd partials
// ---------------------------------------------------------------------------

typedef __bf16 bf16x8 __attribute__((ext_vector_type(8)));
typedef __bf16 bf16x4 __attribute__((ext_vector_type(4)));
typedef float floatx4 __attribute__((ext_vector_type(4)));

#define S_TOTAL 13294
#define M_ROWS  26588
#define M_PAD   26624

#define MFMA16(a, b, c) __builtin_amdgcn_mfma_f32_16x16x32_bf16(a, b, c, 0, 0, 0)

// ---------------- weight transpose: 64x64 tiles via LDS --------------------
__global__ __launch_bounds__(256) void cvt_k(
    const float* __restrict__ Woff, const float* __restrict__ Wattn,
    const float* __restrict__ Wval, const float* __restrict__ Wout,
    const float* __restrict__ W1,   const float* __restrict__ W2,
    const float* __restrict__ boff, const float* __restrict__ battn,
    __bf16* __restrict__ wbase, float* __restrict__ bc) {
    int b = blockIdx.x;
    if (b >= 184) {
        for (int i = threadIdx.x; i < 384; i += 256)
            bc[i] = (i < 256) ? boff[i] : battn[i - 256];
        return;
    }
    const float* W; __bf16* D; int K, N, t;
    if (b < 16)       { W = Woff;  D = wbase;          K = 256;  N = 256;  t = b; }
    else if (b < 24)  { W = Wattn; D = wbase + 65536;  K = 256;  N = 128;  t = b - 16; }
    else if (b < 40)  { W = Wval;  D = wbase + 98304;  K = 256;  N = 256;  t = b - 24; }
    else if (b < 56)  { W = Wout;  D = wbase + 163840; K = 256;  N = 256;  t = b - 40; }
    else if (b < 120) { W = W1;    D = wbase + 229376; K = 256;  N = 1024; t = b - 56; }
    else              { W = W2;    D = wbase + 491520; K = 1024; N = 256;  t = b - 120; }
    int tk = K >> 6;
    int n0 = (t / tk) << 6, k0 = (t % tk) << 6;
    __shared__ float T[64][65];
    int tid = threadIdx.x;
    int rr = tid >> 4, cc = (tid & 15) << 2;
#pragma unroll
    for (int p = 0; p < 4; p++) {
        int r = p * 16 + rr;
        float4 v = *(const float4*)(W + (size_t)(k0 + r) * N + n0 + cc);
        T[r][cc] = v.x; T[r][cc + 1] = v.y; T[r][cc + 2] = v.z; T[r][cc + 3] = v.w;
    }
    __syncthreads();
#pragma unroll
    for (int p = 0; p < 4; p++) {
        int n = p * 16 + rr;
        bf16x4 o = {(__bf16)T[cc][n], (__bf16)T[cc + 1][n],
                    (__bf16)T[cc + 2][n], (__bf16)T[cc + 3][n]};
        *(bf16x4*)(D + (size_t)(n0 + n) * K + k0 + cc) = o;
    }
}

// ---------------- GEMM, A staged from f32 (BM=32, prefetched B) ------------
template <int J, bool SUMPOS, bool BF16OUT>
__global__ __launch_bounds__(512, 4) void gemm_src(
    const float* __restrict__ Af, const float* __restrict__ Pf,
    const __bf16* __restrict__ BT, const float* __restrict__ bias,
    float* __restrict__ Cf, __bf16* __restrict__ Cb, int N) {
    constexpr int ASTR = 264;
    __shared__ __align__(16) __bf16 As[32 * ASTR];
    const int tid = threadIdx.x, wave = tid >> 6, lane = tid & 63;
    const int l16 = lane & 15, quad = lane >> 4;
    const int row0 = blockIdx.x * 32;
#pragma unroll
    for (int p = 0; p < 4; p++) {                    // stage+convert A
        int fe = (p * 512 + tid) * 4;
        int m = fe >> 8, k = fe & 255;
        int row = min(row0 + m, M_ROWS - 1);
        float4 s = *(const float4*)(Af + (size_t)row * 256 + k);
        if (SUMPOS) {
            float4 pp = *(const float4*)(Pf + (size_t)row * 256 + k);
            s.x += pp.x; s.y += pp.y; s.z += pp.z; s.w += pp.w;
        }
        bf16x4 v = {(__bf16)s.x, (__bf16)s.y, (__bf16)s.z, (__bf16)s.w};
        *(bf16x4*)(As + m * ASTR + k) = v;
    }
    __syncthreads();
    const int n0 = wave * (J * 16);
    floatx4 acc[2][J] = {};
    bf16x8 bb[2][J];
#pragma unroll
    for (int j = 0; j < J; j++)
        bb[0][j] = *(const bf16x8*)(BT + (size_t)(n0 + j * 16 + l16) * 256 + quad * 8);
#pragma unroll
    for (int ki = 0; ki < 8; ki++) {
        const int cur = ki & 1;
        if (ki < 7) {
#pragma unroll
            for (int j = 0; j < J; j++)
                bb[cur ^ 1][j] = *(const bf16x8*)(BT + (size_t)(n0 + j * 16 + l16) * 256
                                                  + (ki + 1) * 32 + quad * 8);
        }
        bf16x8 af[2];
#pragma unroll
        for (int i = 0; i < 2; i++)
            af[i] = *(const bf16x8*)(As + (i * 16 + l16) * ASTR + ki * 32 + quad * 8);
#pragma unroll
        for (int i = 0; i < 2; i++)
#pragma unroll
            for (int j = 0; j < J; j++)
                acc[i][j] = MFMA16(af[i], bb[cur][j], acc[i][j]);
    }
    float bv[J];
#pragma unroll
    for (int j = 0; j < J; j++) bv[j] = bias[n0 + j * 16 + l16];
#pragma unroll
    for (int i = 0; i < 2; i++)
#pragma unroll
        for (int j = 0; j < J; j++)
#pragma unroll
            for (int r = 0; r < 4; r++) {
                float v = acc[i][j][r] + bv[j];
                size_t gi = (size_t)(row0 + i * 16 + quad * 4 + r) * N + n0 + j * 16 + l16;
                if (BF16OUT) Cb[gi] = (__bf16)v;
                else         Cf[gi] = v;
            }
}

// ---------------- MSDeformAttn sampling (unchanged) ------------------------
__global__ __launch_bounds__(256) void sample_k(const float* __restrict__ offa,
                                                const __bf16* __restrict__ valb,
                                                const float* __restrict__ refp,
                                                __bf16* __restrict__ outb) {
    const int r   = blockIdx.x;
    const int tid = threadIdx.x;
    if (r >= M_ROWS) {
        outb[(size_t)r * 256 + tid] = (__bf16)0.f;
        return;
    }
    __shared__ float2 s_wo[4][128];
    const int n = (r >= S_TOTAL) ? 1 : 0;

    if (tid < 128) {
        const int HLc[4] = {100, 50, 25, 13};
        const int STc[4] = {0, 10000, 12500, 13125};
        int lp = tid & 15, l = lp >> 2;
        float logit = offa[(size_t)r * 384 + 256 + tid];
        float mx = logit;
        mx = fmaxf(mx, __shfl_xor(mx, 1));
        mx = fmaxf(mx, __shfl_xor(mx, 2));
        mx = fmaxf(mx, __shfl_xor(mx, 4));
        mx = fmaxf(mx, __shfl_xor(mx, 8));
        float e = __expf(logit - mx);
        float s = e;
        s += __shfl_xor(s, 1); s += __shfl_xor(s, 2);
        s += __shfl_xor(s, 4); s += __shfl_xor(s, 8);
        float aw = e / s;

        float2 o2 = *(const float2*)(offa + (size_t)r * 384 + tid * 2);
        float rx = refp[((size_t)r * 4 + l) * 2];
        float ry = refp[((size_t)r * 4 + l) * 2 + 1];
        int   Wl = HLc[l];
        float x = rx * (float)Wl + o2.x - 0.5f;
        float y = ry * (float)Wl + o2.y - 0.5f;
        float xf = floorf(x), yf = floorf(y);
        float wx1 = x - xf, wy1 = y - yf;
        float wx0 = 1.f - wx1, wy0 = 1.f - wy1;
        int x0 = (int)xf, y0 = (int)yf;
        int base = n * S_TOTAL + STc[l];
#pragma unroll
        for (int c = 0; c < 4; c++) {
            int yy = y0 + (c >> 1), xx = x0 + (c & 1);
            bool valid = (yy >= 0) & (yy < Wl) & (xx >= 0) & (xx < Wl);
            int yc = min(max(yy, 0), Wl - 1);
            int xc = min(max(xx, 0), Wl - 1);
            float w = ((c >> 1) ? wy1 : wy0) * ((c & 1) ? wx1 : wx0);
            int off = (base + yc * Wl + xc) * 512;
            s_wo[c][tid] = make_float2(valid ? w * aw : 0.f, __int_as_float(off));
        }
    }
    __syncthreads();

    const int h  = tid >> 5;
    const int pg = (tid >> 2) & 7;
    const int cg = tid & 3;
    const char* vbase = (const char*)valb + h * 64 + cg * 16;
    float a[8] = {};
#pragma unroll
    for (int pp = 0; pp < 2; pp++) {
        int idx = h * 16 + pg * 2 + pp;
#pragma unroll
        for (int c = 0; c < 4; c++) {
            float2 wo = s_wo[c][idx];
            float  w  = wo.x;
            bf16x8 v  = *(const bf16x8*)(vbase + __float_as_int(wo.y));
#pragma unroll
            for (int k = 0; k < 8; k++) a[k] += w * (float)v[k];
        }
    }
#pragma unroll
    for (int k = 0; k < 8; k++) {
        a[k] += __shfl_xor(a[k], 4);
        a[k] += __shfl_xor(a[k], 8);
        a[k] += __shfl_xor(a[k], 16);
    }
    if (pg == 0) {
        bf16x8 res;
#pragma unroll
        for (int k = 0; k < 8; k++) res[k] = (__bf16)a[k];
        *(bf16x8*)(outb + (size_t)r * 256 + h * 32 + cg * 8) = res;
    }
}

// ---------------- fused out-proj + residual + LN1 (BM=32) ------------------
__global__ __launch_bounds__(512, 4) void oln_k(
    const __bf16* __restrict__ A, const __bf16* __restrict__ BT,
    const float* __restrict__ bias, const float* __restrict__ src,
    const float* __restrict__ g, const float* __restrict__ be,
    float* __restrict__ x, __bf16* __restrict__ xb) {
    constexpr int ASTR = 264;
    __shared__ __align__(16) __bf16 As[32 * ASTR];
    __shared__ float rs[32], rq[32];
    const int tid = threadIdx.x, wave = tid >> 6, lane = tid & 63;
    const int l16 = lane & 15, quad = lane >> 4;
    const int row0 = blockIdx.x * 32;
#pragma unroll
    for (int p = 0; p < 2; p++) {
        int fg = p * 512 + tid;
        int m = fg >> 5, gg = fg & 31;
        *(bf16x8*)(As + m * ASTR + gg * 8) =
            *(const bf16x8*)(A + (size_t)(row0 + m) * 256 + gg * 8);
    }
    if (tid < 32) { rs[tid] = 0.f; rq[tid] = 0.f; }
    __syncthreads();
    const int n0 = wave * 32;
    floatx4 acc[2][2] = {};
    bf16x8 bb[2][2];
#pragma unroll
    for (int j = 0; j < 2; j++)
        bb[0][j] = *(const bf16x8*)(BT + (size_t)(n0 + j * 16 + l16) * 256 + quad * 8);
#pragma unroll
    for (int ki = 0; ki < 8; ki++) {
        const int cur = ki & 1;
        if (ki < 7) {
#pragma unroll
            for (int j = 0; j < 2; j++)
                bb[cur ^ 1][j] = *(const bf16x8*)(BT + (size_t)(n0 + j * 16 + l16) * 256
                                                  + (ki + 1) * 32 + quad * 8);
        }
        bf16x8 af[2];
#pragma unroll
        for (int i = 0; i < 2; i++)
            af[i] = *(const bf16x8*)(As + (i * 16 + l16) * ASTR + ki * 32 + quad * 8);
#pragma unroll
        for (int i = 0; i < 2; i++)
#pragma unroll
            for (int j = 0; j < 2; j++)
                acc[i][j] = MFMA16(af[i], bb[cur][j], acc[i][j]);
    }
    float bv[2], gv[2], bev[2];
#pragma unroll
    for (int j = 0; j < 2; j++) {
        bv[j]  = bias[n0 + j * 16 + l16];
        gv[j]  = g[n0 + j * 16 + l16];
        bev[j] = be[n0 + j * 16 + l16];
    }
    float vals[2][2][4];
#pragma unroll
    for (int i = 0; i < 2; i++)
#pragma unroll
        for (int r = 0; r < 4; r++) {
            int lrow = i * 16 + quad * 4 + r;
            int rowc = min(row0 + lrow, M_ROWS - 1);
            float s = 0.f, q = 0.f;
#pragma unroll
            for (int j = 0; j < 2; j++) {
                float v = acc[i][j][r] + bv[j]
                        + src[(size_t)rowc * 256 + n0 + j * 16 + l16];
                vals[i][j][r] = v;
                s += v; q += v * v;
            }
            s += __shfl_xor(s, 1); s += __shfl_xor(s, 2);
            s += __shfl_xor(s, 4); s += __shfl_xor(s, 8);
            q += __shfl_xor(q, 1); q += __shfl_xor(q, 2);
            q += __shfl_xor(q, 4); q += __shfl_xor(q, 8);
            if (l16 == 0) { atomicAdd(&rs[lrow], s); atomicAdd(&rq[lrow], q); }
        }
    __syncthreads();
#pragma unroll
    for (int i = 0; i < 2; i++)
#pragma unroll
        for (int r = 0; r < 4; r++) {
            int lrow = i * 16 + quad * 4 + r;
            float mean = rs[lrow] * (1.f / 256.f);
            float var  = rq[lrow] * (1.f / 256.f) - mean * mean;
            float rstd = rsqrtf(var + 1e-5f);
#pragma unroll
            for (int j = 0; j < 2; j++) {
                float o = (vals[i][j][r] - mean) * rstd * gv[j] + bev[j];
                size_t gi = (size_t)(row0 + lrow) * 256 + n0 + j * 16 + l16;
                x[gi]  = o;
                xb[gi] = (__bf16)o;
            }
        }
}

// ---------------- fused FFN + residual + LN2 (BM=32, 4 h-quarters) ---------
__global__ __launch_bounds__(512, 4) void ffn_k(
    const __bf16* __restrict__ xb, const __bf16* __restrict__ W1T,
    const __bf16* __restrict__ W2T, const float* __restrict__ b1,
    const float* __restrict__ b2, const float* __restrict__ x,
    const float* __restrict__ g, const float* __restrict__ be,
    float* __restrict__ out) {
    constexpr int ASTR = 264, HSTR = 264;
    __shared__ __align__(16) __bf16 As[32 * ASTR];   // 16.5 KB
    __shared__ __align__(16) __bf16 Hs[32 * HSTR];   // 16.5 KB
    __shared__ float rs[32], rq[32];
    const int tid = threadIdx.x, wave = tid >> 6, lane = tid & 63;
    const int l16 = lane & 15, quad = lane >> 4;
    const int row0 = blockIdx.x * 32;
#pragma unroll
    for (int p = 0; p < 2; p++) {
        int fg = p * 512 + tid;
        int m = fg >> 5, gg = fg & 31;
        *(bf16x8*)(As + m * ASTR + gg * 8) =
            *(const bf16x8*)(xb + (size_t)(row0 + m) * 256 + gg * 8);
    }
    if (tid < 32) { rs[tid] = 0.f; rq[tid] = 0.f; }
    __syncthreads();

    float b1v[4][2];
#pragma unroll
    for (int hc = 0; hc < 4; hc++)
#pragma unroll
        for (int j = 0; j < 2; j++)
            b1v[hc][j] = b1[hc * 256 + wave * 32 + j * 16 + l16];

    floatx4 facc[2][2] = {};
#pragma unroll
    for (int hc = 0; hc < 4; hc++) {
        // ---- FFN1 quarter: hacc = A @ W1[:, hc*256 .. +256) ---------------
        floatx4 hacc[2][2] = {};
        {
            bf16x8 wb[2][2];
#pragma unroll
            for (int j = 0; j < 2; j++)
                wb[0][j] = *(const bf16x8*)(W1T
                    + (size_t)(hc * 256 + wave * 32 + j * 16 + l16) * 256 + quad * 8);
#pragma unroll
            for (int ki = 0; ki < 8; ki++) {
                const int cur = ki & 1;
                if (ki < 7) {
#pragma unroll
                    for (int j = 0; j < 2; j++)
                        wb[cur ^ 1][j] = *(const bf16x8*)(W1T
                            + (size_t)(hc * 256 + wave * 32 + j * 16 + l16) * 256
                            + (ki + 1) * 32 + quad * 8);
                }
                bf16x8 af[2];
#pragma unroll
                for (int i = 0; i < 2; i++)
                    af[i] = *(const bf16x8*)(As + (i * 16 + l16) * ASTR + ki * 32 + quad * 8);
#pragma unroll
                for (int i = 0; i < 2; i++)
#pragma unroll
                    for (int j = 0; j < 2; j++)
                        hacc[i][j] = MFMA16(af[i], wb[cur][j], hacc[i][j]);
            }
        }
        __syncthreads();              // prior quarter's Hs reads done
        // direct C-layout scatter: Hs[row][col] = relu(hacc + b1), bf16
#pragma unroll
        for (int i = 0; i < 2; i++)
#pragma unroll
            for (int j = 0; j < 2; j++)
#pragma unroll
                for (int r = 0; r < 4; r++)
                    Hs[(i * 16 + quad * 4 + r) * HSTR + wave * 32 + j * 16 + l16] =
                        (__bf16)fmaxf(hacc[i][j][r] + b1v[hc][j], 0.f);
        __syncthreads();              // Hs visible
        // ---- FFN2 quarter: facc += Hs @ W2[hc*256 .. +256, :] -------------
        {
            bf16x8 wb[2][2];
#pragma unroll
            for (int j = 0; j < 2; j++)
                wb[0][j] = *(const bf16x8*)(W2T
                    + (size_t)(wave * 32 + j * 16 + l16) * 1024 + hc * 256 + quad * 8);
#pragma unroll
            for (int ki = 0; ki < 8; ki++) {
                const int cur = ki & 1;
                if (ki < 7) {
#pragma unroll
                    for (int j = 0; j < 2; j++)
                        wb[cur ^ 1][j] = *(const bf16x8*)(W2T
                            + (size_t)(wave * 32 + j * 16 + l16) * 1024
                            + hc * 256 + (ki + 1) * 32 + quad * 8);
                }
                bf16x8 ah[2];
#pragma unroll
                for (int i = 0; i < 2; i++)
                    ah[i] = *(const bf16x8*)(Hs + (i * 16 + l16) * HSTR + ki * 32 + quad * 8);
#pragma unroll
                for (int i = 0; i < 2; i++)
#pragma unroll
                    for (int j = 0; j < 2; j++)
                        facc[i][j] = MFMA16(ah[i], wb[cur][j], facc[i][j]);
            }
        }
    }
    // ---- epilogue: +b2 +x residual, LN2, store out ------------------------
    const int n0 = wave * 32;
    float b2v[2], gv[2], bev[2];
#pragma unroll
    for (int j = 0; j < 2; j++) {
        b2v[j] = b2[n0 + j * 16 + l16];
        gv[j]  = g[n0 + j * 16 + l16];
        bev[j] = be[n0 + j * 16 + l16];
    }
    float vals[2][2][4];
#pragma unroll
    for (int i = 0; i < 2; i++)
#pragma unroll
        for (int r = 0; r < 4; r++) {
            int lrow = i * 16 + quad * 4 + r;
            float s = 0.f, q = 0.f;
#pragma unroll
            for (int j = 0; j < 2; j++) {
                float v = facc[i][j][r] + b2v[j]
                        + x[(size_t)(row0 + lrow) * 256 + n0 + j * 16 + l16];
                vals[i][j][r] = v;
                s += v; q += v * v;
            }
            s += __shfl_xor(s, 1); s += __shfl_xor(s, 2);
            s += __shfl_xor(s, 4); s += __shfl_xor(s, 8);
            q += __shfl_xor(q, 1); q += __shfl_xor(q, 2);
            q += __shfl_xor(q, 4); q += __shfl_xor(q, 8);
            if (l16 == 0) { atomicAdd(&rs[lrow], s); atomicAdd(&rq[lrow], q); }
        }
    __syncthreads();
#pragma unroll
    for (int i = 0; i < 2; i++)
#pragma unroll
        for (int r = 0; r < 4; r++) {
            int lrow = i * 16 + quad * 4 + r;
            int row  = row0 + lrow;
            if (row < M_ROWS) {
                float mean = rs[lrow] * (1.f / 256.f);
                float var  = rq[lrow] * (1.f / 256.f) - mean * mean;
                float rstd = rsqrtf(var + 1e-5f);
#pragma unroll
                for (int j = 0; j < 2; j++) {
                    float o = (vals[i][j][r] - mean) * rstd * gv[j] + bev[j];
                    out[(size_t)row * 256 + n0 + j * 16 + l16] = o;
                }
            }
        }
}

// ---------------------------------------------------------------------------
extern "C" void kernel_launch(void* const* d_in, const int* in_sizes, int n_in,
                              void* d_out, int out_size, void* d_ws, size_t ws_size,
                              hipStream_t stream) {
    const float* src  = (const float*)d_in[0];
    const float* pos  = (const float*)d_in[1];
    const float* refp = (const float*)d_in[2];
    const float* W_off  = (const float*)d_in[5];
    const float* b_off  = (const float*)d_in[6];
    const float* W_attn = (const float*)d_in[7];
    const float* b_attn = (const float*)d_in[8];
    const float* W_val  = (const float*)d_in[9];
    const float* b_val  = (const float*)d_in[10];
    const float* W_out  = (const float*)d_in[11];
    const float* b_out  = (const float*)d_in[12];
    const float* W1     = (const float*)d_in[13];
    const float* b1     = (const float*)d_in[14];
    const float* W2     = (const float*)d_in[15];
    const float* b2     = (const float*)d_in[16];
    const float* g1     = (const float*)d_in[17];
    const float* beta1  = (const float*)d_in[18];
    const float* g2     = (const float*)d_in[19];
    const float* beta2  = (const float*)d_in[20];
    float* out = (float*)d_out;

    // ---- workspace layout (same proven aliasing as R5, peak ~70 MB) -------
    const size_t RB = (size_t)M_PAD * 256 * 2;
    const size_t RF = (size_t)M_PAD * 256 * 4;
    char* ws = (char*)d_ws;
    __bf16* outb = (__bf16*)(ws);
    __bf16* valb = (__bf16*)(ws + RB);
    float*  offa = (float*)(ws + 2 * RB);             // M_PAD x 384
    float*  x    = (float*)(ws + 2 * RB);             // reuse after sample
    __bf16* xb   = (__bf16*)(ws + 2 * RB + RF);
    char*   regW = ws + 2 * RB + (size_t)M_PAD * 384 * 4;

    __bf16* WTcomb = (__bf16*)regW;
    __bf16* WTval  = (__bf16*)(regW + 196608);
    __bf16* WTout  = (__bf16*)(regW + 327680);
    __bf16* WT1    = (__bf16*)(regW + 458752);
    __bf16* WT2    = (__bf16*)(regW + 983040);
    float*  bc     = (float*)(regW + 1507328);

    cvt_k<<<185, 256, 0, stream>>>(W_off, W_attn, W_val, W_out, W1, W2,
                                   b_off, b_attn, WTcomb, bc);

    gemm_src<3, true, false><<<832, 512, 0, stream>>>(
        src, pos, WTcomb, bc, offa, nullptr, 384);
    gemm_src<2, false, true><<<832, 512, 0, stream>>>(
        src, src, WTval, b_val, nullptr, valb, 256);

    sample_k<<<M_PAD, 256, 0, stream>>>(offa, valb, refp, outb);

    oln_k<<<832, 512, 0, stream>>>(outb, WTout, b_out, src, g1, beta1, x, xb);

    ffn_k<<<832, 512, 0, stream>>>(xb, WT1, WT2, b1, b2, x, g2, beta2, out);
}

// Round 7
// 325.875 us; speedup vs baseline: 1.1986x; 1.1986x over previous
//
#include <hip/hip_runtime.h>

// ---------------------------------------------------------------------------
// DeformableTransformerEncoderLayer on MI355X (gfx950) — round 7
// Theory: all MFMA kernels were bound by per-block WEIGHT RE-READS through
// L2 (BM=32 -> 832 blocks x 1MB = 832MB for ffn alone; R5/R6 identical at
// 133us despite different inner loops). Fix: BM=128 (208 blocks) -> 2.7-4x
// less weight traffic. A-tiles in XOR-swizzled dynamic LDS (64KB); ffn h
// stays in a 32KB LDS chunk (8 x 128-col passes). 512 thr, launch_bounds(,2).
// ---------------------------------------------------------------------------

typedef __bf16 bf16x8 __attribute__((ext_vector_type(8)));
typedef __bf16 bf16x4 __attribute__((ext_vector_type(4)));
typedef float floatx4 __attribute__((ext_vector_type(4)));

#define S_TOTAL 13294
#define M_ROWS  26588
#define M_PAD   26624      // 208 * 128

#define MFMA16(a, b, c) __builtin_amdgcn_mfma_f32_16x16x32_bf16(a, b, c, 0, 0, 0)
// As: 128 rows x 32 granules(16B); swizzled addr in elements
#define SWA(m, g) ((m) * 256 + ((((g) ^ ((m) & 31))) << 3))
// Hs: 128 rows x 16 granules(16B)
#define SWH(r, g) ((r) * 128 + ((((g) ^ ((r) & 15))) << 3))

// ---------------- weight transpose: 64x64 tiles via LDS --------------------
__global__ __launch_bounds__(256) void cvt_k(
    const float* __restrict__ Woff, const float* __restrict__ Wattn,
    const float* __restrict__ Wval, const float* __restrict__ Wout,
    const float* __restrict__ W1,   const float* __restrict__ W2,
    const float* __restrict__ boff, const float* __restrict__ battn,
    __bf16* __restrict__ wbase, float* __restrict__ bc) {
    int b = blockIdx.x;
    if (b >= 184) {
        for (int i = threadIdx.x; i < 384; i += 256)
            bc[i] = (i < 256) ? boff[i] : battn[i - 256];
        return;
    }
    const float* W; __bf16* D; int K, N, t;
    if (b < 16)       { W = Woff;  D = wbase;          K = 256;  N = 256;  t = b; }
    else if (b < 24)  { W = Wattn; D = wbase + 65536;  K = 256;  N = 128;  t = b - 16; }
    else if (b < 40)  { W = Wval;  D = wbase + 98304;  K = 256;  N = 256;  t = b - 24; }
    else if (b < 56)  { W = Wout;  D = wbase + 163840; K = 256;  N = 256;  t = b - 40; }
    else if (b < 120) { W = W1;    D = wbase + 229376; K = 256;  N = 1024; t = b - 56; }
    else              { W = W2;    D = wbase + 491520; K = 1024; N = 256;  t = b - 120; }
    int tk = K >> 6;
    int n0 = (t / tk) << 6, k0 = (t % tk) << 6;
    __shared__ float T[64][65];
    int tid = threadIdx.x;
    int rr = tid >> 4, cc = (tid & 15) << 2;
#pragma unroll
    for (int p = 0; p < 4; p++) {
        int r = p * 16 + rr;
        float4 v = *(const float4*)(W + (size_t)(k0 + r) * N + n0 + cc);
        T[r][cc] = v.x; T[r][cc + 1] = v.y; T[r][cc + 2] = v.z; T[r][cc + 3] = v.w;
    }
    __syncthreads();
#pragma unroll
    for (int p = 0; p < 4; p++) {
        int n = p * 16 + rr;
        bf16x4 o = {(__bf16)T[cc][n], (__bf16)T[cc + 1][n],
                    (__bf16)T[cc + 2][n], (__bf16)T[cc + 3][n]};
        *(bf16x4*)(D + (size_t)(n0 + n) * K + k0 + cc) = o;
    }
}

// ---------------- GEMM, BM=128, A staged from f32 --------------------------
// dyn smem: As 64KB swizzled. 8 waves, wave N-strip = J*16. C = A@B + bias.
template <int J, bool SUMPOS, bool BF16OUT>
__global__ __launch_bounds__(512, 2) void gemm_src(
    const float* __restrict__ Af, const float* __restrict__ Pf,
    const __bf16* __restrict__ BT, const float* __restrict__ bias,
    float* __restrict__ Cf, __bf16* __restrict__ Cb, int N) {
    extern __shared__ __align__(16) char smem[];
    __bf16* As = (__bf16*)smem;
    const int tid = threadIdx.x, wave = tid >> 6, lane = tid & 63;
    const int l16 = lane & 15, quad = lane >> 4;
    const int row0 = blockIdx.x * 128;
#pragma unroll
    for (int p = 0; p < 8; p++) {                // stage+convert A (f32->bf16)
        int fg = p * 512 + tid;
        int m = fg >> 5, gn = fg & 31;
        int row = min(row0 + m, M_ROWS - 1);
        const float* sp = Af + (size_t)row * 256 + gn * 8;
        float4 a0 = *(const float4*)sp;
        float4 a1 = *(const float4*)(sp + 4);
        if (SUMPOS) {
            const float* pp = Pf + (size_t)row * 256 + gn * 8;
            float4 p0 = *(const float4*)pp;
            float4 p1 = *(const float4*)(pp + 4);
            a0.x += p0.x; a0.y += p0.y; a0.z += p0.z; a0.w += p0.w;
            a1.x += p1.x; a1.y += p1.y; a1.z += p1.z; a1.w += p1.w;
        }
        bf16x8 v = {(__bf16)a0.x, (__bf16)a0.y, (__bf16)a0.z, (__bf16)a0.w,
                    (__bf16)a1.x, (__bf16)a1.y, (__bf16)a1.z, (__bf16)a1.w};
        *(bf16x8*)(As + SWA(m, gn)) = v;
    }
    __syncthreads();
    const int n0 = wave * (J * 16);
    floatx4 acc[8][J] = {};
    bf16x8 bb[2][J];
#pragma unroll
    for (int j = 0; j < J; j++)
        bb[0][j] = *(const bf16x8*)(BT + (size_t)(n0 + j * 16 + l16) * 256 + quad * 8);
#pragma unroll
    for (int ki = 0; ki < 8; ki++) {
        const int cur = ki & 1;
        if (ki < 7) {
#pragma unroll
            for (int j = 0; j < J; j++)
                bb[cur ^ 1][j] = *(const bf16x8*)(BT + (size_t)(n0 + j * 16 + l16) * 256
                                                  + (ki + 1) * 32 + quad * 8);
        }
#pragma unroll
        for (int i = 0; i < 8; i++) {
            int m = i * 16 + l16;
            bf16x8 af = *(const bf16x8*)(As + SWA(m, ki * 4 + quad));
#pragma unroll
            for (int j = 0; j < J; j++)
                acc[i][j] = MFMA16(af, bb[cur][j], acc[i][j]);
        }
    }
    float bv[J];
#pragma unroll
    for (int j = 0; j < J; j++) bv[j] = bias[n0 + j * 16 + l16];
#pragma unroll
    for (int i = 0; i < 8; i++)
#pragma unroll
        for (int j = 0; j < J; j++)
#pragma unroll
            for (int r = 0; r < 4; r++) {
                float v = acc[i][j][r] + bv[j];
                size_t gi = (size_t)(row0 + i * 16 + quad * 4 + r) * N + n0 + j * 16 + l16;
                if (BF16OUT) Cb[gi] = (__bf16)v;
                else         Cf[gi] = v;
            }
}

// ---------------- MSDeformAttn sampling (unchanged) ------------------------
__global__ __launch_bounds__(256) void sample_k(const float* __restrict__ offa,
                                                const __bf16* __restrict__ valb,
                                                const float* __restrict__ refp,
                                                __bf16* __restrict__ outb) {
    const int r   = blockIdx.x;
    const int tid = threadIdx.x;
    if (r >= M_ROWS) {
        outb[(size_t)r * 256 + tid] = (__bf16)0.f;
        return;
    }
    __shared__ float2 s_wo[4][128];
    const int n = (r >= S_TOTAL) ? 1 : 0;

    if (tid < 128) {
        const int HLc[4] = {100, 50, 25, 13};
        const int STc[4] = {0, 10000, 12500, 13125};
        int lp = tid & 15, l = lp >> 2;
        float logit = offa[(size_t)r * 384 + 256 + tid];
        float mx = logit;
        mx = fmaxf(mx, __shfl_xor(mx, 1));
        mx = fmaxf(mx, __shfl_xor(mx, 2));
        mx = fmaxf(mx, __shfl_xor(mx, 4));
        mx = fmaxf(mx, __shfl_xor(mx, 8));
        float e = __expf(logit - mx);
        float s = e;
        s += __shfl_xor(s, 1); s += __shfl_xor(s, 2);
        s += __shfl_xor(s, 4); s += __shfl_xor(s, 8);
        float aw = e / s;

        float2 o2 = *(const float2*)(offa + (size_t)r * 384 + tid * 2);
        float rx = refp[((size_t)r * 4 + l) * 2];
        float ry = refp[((size_t)r * 4 + l) * 2 + 1];
        int   Wl = HLc[l];
        float x = rx * (float)Wl + o2.x - 0.5f;
        float y = ry * (float)Wl + o2.y - 0.5f;
        float xf = floorf(x), yf = floorf(y);
        float wx1 = x - xf, wy1 = y - yf;
        float wx0 = 1.f - wx1, wy0 = 1.f - wy1;
        int x0 = (int)xf, y0 = (int)yf;
        int base = n * S_TOTAL + STc[l];
#pragma unroll
        for (int c = 0; c < 4; c++) {
            int yy = y0 + (c >> 1), xx = x0 + (c & 1);
            bool valid = (yy >= 0) & (yy < Wl) & (xx >= 0) & (xx < Wl);
            int yc = min(max(yy, 0), Wl - 1);
            int xc = min(max(xx, 0), Wl - 1);
            float w = ((c >> 1) ? wy1 : wy0) * ((c & 1) ? wx1 : wx0);
            int off = (base + yc * Wl + xc) * 512;
            s_wo[c][tid] = make_float2(valid ? w * aw : 0.f, __int_as_float(off));
        }
    }
    __syncthreads();

    const int h  = tid >> 5;
    const int pg = (tid >> 2) & 7;
    const int cg = tid & 3;
    const char* vbase = (const char*)valb + h * 64 + cg * 16;
    float a[8] = {};
#pragma unroll
    for (int pp = 0; pp < 2; pp++) {
        int idx = h * 16 + pg * 2 + pp;
#pragma unroll
        for (int c = 0; c < 4; c++) {
            float2 wo = s_wo[c][idx];
            float  w  = wo.x;
            bf16x8 v  = *(const bf16x8*)(vbase + __float_as_int(wo.y));
#pragma unroll
            for (int k = 0; k < 8; k++) a[k] += w * (float)v[k];
        }
    }
#pragma unroll
    for (int k = 0; k < 8; k++) {
        a[k] += __shfl_xor(a[k], 4);
        a[k] += __shfl_xor(a[k], 8);
        a[k] += __shfl_xor(a[k], 16);
    }
    if (pg == 0) {
        bf16x8 res;
#pragma unroll
        for (int k = 0; k < 8; k++) res[k] = (__bf16)a[k];
        *(bf16x8*)(outb + (size_t)r * 256 + h * 32 + cg * 8) = res;
    }
}

// ---------------- fused out-proj + residual + LN1 (BM=128) -----------------
__global__ __launch_bounds__(512, 2) void oln_k(
    const __bf16* __restrict__ A, const __bf16* __restrict__ BT,
    const float* __restrict__ bias, const float* __restrict__ src,
    const float* __restrict__ g, const float* __restrict__ be,
    float* __restrict__ x, __bf16* __restrict__ xb) {
    extern __shared__ __align__(16) char smem[];
    __bf16* As = (__bf16*)smem;                 // 64 KB
    float*  rs = (float*)(smem + 65536);        // 128
    float*  rq = rs + 128;
    const int tid = threadIdx.x, wave = tid >> 6, lane = tid & 63;
    const int l16 = lane & 15, quad = lane >> 4;
    const int row0 = blockIdx.x * 128;
#pragma unroll
    for (int p = 0; p < 8; p++) {
        int fg = p * 512 + tid;
        int m = fg >> 5, gn = fg & 31;
        *(bf16x8*)(As + SWA(m, gn)) =
            *(const bf16x8*)(A + (size_t)(row0 + m) * 256 + gn * 8);
    }
    if (tid < 128) { rs[tid] = 0.f; rq[tid] = 0.f; }
    __syncthreads();
    const int n0 = wave * 32;
    floatx4 acc[8][2] = {};
    bf16x8 bb[2][2];
#pragma unroll
    for (int j = 0; j < 2; j++)
        bb[0][j] = *(const bf16x8*)(BT + (size_t)(n0 + j * 16 + l16) * 256 + quad * 8);
#pragma unroll
    for (int ki = 0; ki < 8; ki++) {
        const int cur = ki & 1;
        if (ki < 7) {
#pragma unroll
            for (int j = 0; j < 2; j++)
                bb[cur ^ 1][j] = *(const bf16x8*)(BT + (size_t)(n0 + j * 16 + l16) * 256
                                                  + (ki + 1) * 32 + quad * 8);
        }
#pragma unroll
        for (int i = 0; i < 8; i++) {
            int m = i * 16 + l16;
            bf16x8 af = *(const bf16x8*)(As + SWA(m, ki * 4 + quad));
#pragma unroll
            for (int j = 0; j < 2; j++)
                acc[i][j] = MFMA16(af, bb[cur][j], acc[i][j]);
        }
    }
    float bv[2], gv[2], bev[2];
#pragma unroll
    for (int j = 0; j < 2; j++) {
        bv[j]  = bias[n0 + j * 16 + l16];
        gv[j]  = g[n0 + j * 16 + l16];
        bev[j] = be[n0 + j * 16 + l16];
    }
    float vals[8][2][4];
#pragma unroll
    for (int i = 0; i < 8; i++)
#pragma unroll
        for (int r = 0; r < 4; r++) {
            int lrow = i * 16 + quad * 4 + r;
            int rowc = min(row0 + lrow, M_ROWS - 1);
            float s = 0.f, q = 0.f;
#pragma unroll
            for (int j = 0; j < 2; j++) {
                float v = acc[i][j][r] + bv[j]
                        + src[(size_t)rowc * 256 + n0 + j * 16 + l16];
                vals[i][j][r] = v;
                s += v; q += v * v;
            }
            s += __shfl_xor(s, 1); s += __shfl_xor(s, 2);
            s += __shfl_xor(s, 4); s += __shfl_xor(s, 8);
            q += __shfl_xor(q, 1); q += __shfl_xor(q, 2);
            q += __shfl_xor(q, 4); q += __shfl_xor(q, 8);
            if (l16 == 0) { atomicAdd(&rs[lrow], s); atomicAdd(&rq[lrow], q); }
        }
    __syncthreads();
#pragma unroll
    for (int i = 0; i < 8; i++)
#pragma unroll
        for (int r = 0; r < 4; r++) {
            int lrow = i * 16 + quad * 4 + r;
            float mean = rs[lrow] * (1.f / 256.f);
            float var  = rq[lrow] * (1.f / 256.f) - mean * mean;
            float rstd = rsqrtf(var + 1e-5f);
#pragma unroll
            for (int j = 0; j < 2; j++) {
                float o = (vals[i][j][r] - mean) * rstd * gv[j] + bev[j];
                size_t gi = (size_t)(row0 + lrow) * 256 + n0 + j * 16 + l16;
                x[gi]  = o;
                xb[gi] = (__bf16)o;
            }
        }
}

// ---------------- fused FFN + residual + LN2 (BM=128) ----------------------
// dyn smem: As 64KB + Hs 32KB (128-col h-chunk) + rs/rq. Waves: 2 M-groups
// (rows 0-63 / 64-127) x 4 strip-waves. 8 h-chunks of 128 cols.
__global__ __launch_bounds__(512, 2) void ffn_k(
    const __bf16* __restrict__ xb, const __bf16* __restrict__ W1T,
    const __bf16* __restrict__ W2T, const float* __restrict__ b1,
    const float* __restrict__ b2, const float* __restrict__ x,
    const float* __restrict__ g, const float* __restrict__ be,
    float* __restrict__ out) {
    extern __shared__ __align__(16) char smem[];
    __bf16* As = (__bf16*)smem;                 // 64 KB
    __bf16* Hs = (__bf16*)(smem + 65536);       // 32 KB
    float*  rs = (float*)(smem + 98304);        // 128
    float*  rq = rs + 128;
    const int tid = threadIdx.x, wave = tid >> 6, lane = tid & 63;
    const int l16 = lane & 15, quad = lane >> 4;
    const int grp = wave >> 2;                  // row group: 0 / 1
    const int wq  = wave & 3;                   // strip within group
    const int row0 = blockIdx.x * 128;
#pragma unroll
    for (int p = 0; p < 8; p++) {
        int fg = p * 512 + tid;
        int m = fg >> 5, gn = fg & 31;
        *(bf16x8*)(As + SWA(m, gn)) =
            *(const bf16x8*)(xb + (size_t)(row0 + m) * 256 + gn * 8);
    }
    if (tid < 128) { rs[tid] = 0.f; rq[tid] = 0.f; }
    __syncthreads();

    floatx4 facc[4][4] = {};
    for (int ch = 0; ch < 8; ch++) {
        // ---- FFN1: hacc = A(grp rows) @ W1[:, ch*128 + wq*32 .. +32) ------
        const int hc0 = ch * 128 + wq * 32;
        floatx4 hacc[4][2] = {};
        bf16x8 wb[2][2];
#pragma unroll
        for (int j = 0; j < 2; j++)
            wb[0][j] = *(const bf16x8*)(W1T + (size_t)(hc0 + j * 16 + l16) * 256 + quad * 8);
#pragma unroll
        for (int ki = 0; ki < 8; ki++) {
            const int cur = ki & 1;
            if (ki < 7) {
#pragma unroll
                for (int j = 0; j < 2; j++)
                    wb[cur ^ 1][j] = *(const bf16x8*)(W1T
                        + (size_t)(hc0 + j * 16 + l16) * 256 + (ki + 1) * 32 + quad * 8);
            }
#pragma unroll
            for (int i = 0; i < 4; i++) {
                int m = grp * 64 + i * 16 + l16;
                bf16x8 af = *(const bf16x8*)(As + SWA(m, ki * 4 + quad));
#pragma unroll
                for (int j = 0; j < 2; j++)
                    hacc[i][j] = MFMA16(af, wb[cur][j], hacc[i][j]);
            }
        }
        __syncthreads();        // all waves done reading prev chunk's Hs
        float b1v[2];
#pragma unroll
        for (int j = 0; j < 2; j++) b1v[j] = b1[hc0 + j * 16 + l16];
#pragma unroll
        for (int i = 0; i < 4; i++)
#pragma unroll
            for (int j = 0; j < 2; j++)
#pragma unroll
                for (int r = 0; r < 4; r++) {
                    int rr = grp * 64 + i * 16 + quad * 4 + r;
                    int cc = wq * 32 + j * 16 + l16;
                    Hs[SWH(rr, cc >> 3) + (cc & 7)] =
                        (__bf16)fmaxf(hacc[i][j][r] + b1v[j], 0.f);
                }
        __syncthreads();        // Hs chunk visible
        // ---- FFN2: facc += Hs(grp rows, chunk K) @ W2[ch*128.., :] --------
        const int n0 = wq * 64;
        bf16x8 vb[2][4];
#pragma unroll
        for (int j = 0; j < 4; j++)
            vb[0][j] = *(const bf16x8*)(W2T + (size_t)(n0 + j * 16 + l16) * 1024
                                        + ch * 128 + quad * 8);
#pragma unroll
        for (int ki = 0; ki < 4; ki++) {
            const int cur = ki & 1;
            if (ki < 3) {
#pragma unroll
                for (int j = 0; j < 4; j++)
                    vb[cur ^ 1][j] = *(const bf16x8*)(W2T
                        + (size_t)(n0 + j * 16 + l16) * 1024
                        + ch * 128 + (ki + 1) * 32 + quad * 8);
            }
#pragma unroll
            for (int i = 0; i < 4; i++) {
                int rr = grp * 64 + i * 16 + l16;
                bf16x8 ah = *(const bf16x8*)(Hs + SWH(rr, ki * 4 + quad));
#pragma unroll
                for (int j = 0; j < 4; j++)
                    facc[i][j] = MFMA16(ah, vb[cur][j], facc[i][j]);
            }
        }
    }
    // ---- epilogue: +b2 +x residual, LN2, store out ------------------------
    const int n0 = wq * 64;
    float b2v[4], gv[4], bev[4];
#pragma unroll
    for (int j = 0; j < 4; j++) {
        b2v[j] = b2[n0 + j * 16 + l16];
        gv[j]  = g[n0 + j * 16 + l16];
        bev[j] = be[n0 + j * 16 + l16];
    }
    float vals[4][4][4];
#pragma unroll
    for (int i = 0; i < 4; i++)
#pragma unroll
        for (int r = 0; r < 4; r++) {
            int lrow = grp * 64 + i * 16 + quad * 4 + r;
            float s = 0.f, q = 0.f;
#pragma unroll
            for (int j = 0; j < 4; j++) {
                float v = facc[i][j][r] + b2v[j]
                        + x[(size_t)(row0 + lrow) * 256 + n0 + j * 16 + l16];
                vals[i][j][r] = v;
                s += v; q += v * v;
            }
            s += __shfl_xor(s, 1); s += __shfl_xor(s, 2);
            s += __shfl_xor(s, 4); s += __shfl_xor(s, 8);
            q += __shfl_xor(q, 1); q += __shfl_xor(q, 2);
            q += __shfl_xor(q, 4); q += __shfl_xor(q, 8);
            if (l16 == 0) { atomicAdd(&rs[lrow], s); atomicAdd(&rq[lrow], q); }
        }
    __syncthreads();
#pragma unroll
    for (int i = 0; i < 4; i++)
#pragma unroll
        for (int r = 0; r < 4; r++) {
            int lrow = grp * 64 + i * 16 + quad * 4 + r;
            int row  = row0 + lrow;
            if (row < M_ROWS) {
                float mean = rs[lrow] * (1.f / 256.f);
                float var  = rq[lrow] * (1.f / 256.f) - mean * mean;
                float rstd = rsqrtf(var + 1e-5f);
#pragma unroll
                for (int j = 0; j < 4; j++) {
                    float o = (vals[i][j][r] - mean) * rstd * gv[j] + bev[j];
                    out[(size_t)row * 256 + n0 + j * 16 + l16] = o;
                }
            }
        }
}

// ---------------------------------------------------------------------------
extern "C" void kernel_launch(void* const* d_in, const int* in_sizes, int n_in,
                              void* d_out, int out_size, void* d_ws, size_t ws_size,
                              hipStream_t stream) {
    const float* src  = (const float*)d_in[0];
    const float* pos  = (const float*)d_in[1];
    const float* refp = (const float*)d_in[2];
    const float* W_off  = (const float*)d_in[5];
    const float* b_off  = (const float*)d_in[6];
    const float* W_attn = (const float*)d_in[7];
    const float* b_attn = (const float*)d_in[8];
    const float* W_val  = (const float*)d_in[9];
    const float* b_val  = (const float*)d_in[10];
    const float* W_out  = (const float*)d_in[11];
    const float* b_out  = (const float*)d_in[12];
    const float* W1     = (const float*)d_in[13];
    const float* b1     = (const float*)d_in[14];
    const float* W2     = (const float*)d_in[15];
    const float* b2     = (const float*)d_in[16];
    const float* g1     = (const float*)d_in[17];
    const float* beta1  = (const float*)d_in[18];
    const float* g2     = (const float*)d_in[19];
    const float* beta2  = (const float*)d_in[20];
    float* out = (float*)d_out;

    const size_t RB = (size_t)M_PAD * 256 * 2;
    const size_t RF = (size_t)M_PAD * 256 * 4;
    char* ws = (char*)d_ws;
    __bf16* outb = (__bf16*)(ws);
    __bf16* valb = (__bf16*)(ws + RB);
    float*  offa = (float*)(ws + 2 * RB);             // M_PAD x 384
    float*  x    = (float*)(ws + 2 * RB);             // reuse after sample
    __bf16* xb   = (__bf16*)(ws + 2 * RB + RF);
    char*   regW = ws + 2 * RB + (size_t)M_PAD * 384 * 4;

    __bf16* WTcomb = (__bf16*)regW;
    __bf16* WTval  = (__bf16*)(regW + 196608);
    __bf16* WTout  = (__bf16*)(regW + 327680);
    __bf16* WT1    = (__bf16*)(regW + 458752);
    __bf16* WT2    = (__bf16*)(regW + 983040);
    float*  bc     = (float*)(regW + 1507328);

    cvt_k<<<185, 256, 0, stream>>>(W_off, W_attn, W_val, W_out, W1, W2,
                                   b_off, b_attn, WTcomb, bc);

    gemm_src<3, true, false><<<208, 512, 65536, stream>>>(
        src, pos, WTcomb, bc, offa, nullptr, 384);
    gemm_src<2, false, true><<<208, 512, 65536, stream>>>(
        src, src, WTval, b_val, nullptr, valb, 256);

    sample_k<<<M_PAD, 256, 0, stream>>>(offa, valb, refp, outb);

    oln_k<<<208, 512, 66560, stream>>>(outb, WTout, b_out, src, g1, beta1, x, xb);

    ffn_k<<<208, 512, 99328, stream>>>(xb, WT1, WT2, b1, b2, x, g2, beta2, out);
}